// Round 4
// baseline (1490.156 us; speedup 1.0000x reference)
//
#include <hip/hip_runtime.h>
#include <stdint.h>
#include <stddef.h>

// ---------------- problem constants ----------------
// B=2048, F0=39, D=16, layers 128/128/128, xk halves to 64 after each layer.
// GEMM view: M=(b,d), N=s=128, K=(h,k) padded to 39*64=2496 for all layers.
#define F0N    39
#define DN     16
#define SN     128
#define NCHUNK 78                      // 2496 / 32
#define WROW   40                      // bf16 per staged-W row: 32 + 8 pad (80B, 16B-aligned)
#define XROW   72                      // bf16 per X0/XK row: 64 + 8 pad (144B, 16B-aligned)
#define CHUNK_ELEMS (SN * WROW)        // 5120 bf16 = 10240 B per staged chunk
#define PER_LAYER_ELEMS (NCHUNK * CHUNK_ELEMS)
#define TOTCHUNK 234                   // 3 * 78

typedef __attribute__((ext_vector_type(8))) short short8;   // MFMA A/B operand
typedef __attribute__((ext_vector_type(4))) float floatx4;  // MFMA accumulator
typedef __attribute__((ext_vector_type(4))) uint32_t uint4v;

__device__ __forceinline__ uint16_t f2bf(float f) {         // RNE f32->bf16
  uint32_t u = __float_as_uint(f);
  u += 0x7fffu + ((u >> 16) & 1u);
  return (uint16_t)(u >> 16);
}
__device__ __forceinline__ float bf2f(uint16_t b) {
  return __uint_as_float(((uint32_t)b) << 16);
}

// async global->LDS, 16B per lane (wave-uniform base + lane*16 pattern)
__device__ __forceinline__ void load16_lds(const void* g, void* l) {
  __builtin_amdgcn_global_load_lds(
      (__attribute__((address_space(1))) uint32_t*)(uintptr_t)g,
      (__attribute__((address_space(3))) uint32_t*)(uint32_t)(uintptr_t)l,
      16, 0, 0);
}

// ---------------- pre-pass: W fp32 -> bf16, [n][k] layout (R3-verified) ----------------
__global__ __launch_bounds__(256) void cin_prepass(
    const float* __restrict__ w0, const float* __restrict__ w1,
    const float* __restrict__ w2, uint16_t* __restrict__ wout) {
  __shared__ float T[32 * 132];               // [k_in_chunk][n], +4 pad floats per row
  const int bc = blockIdx.x;                  // 0..233
  const int L = bc / NCHUNK;
  const int c = bc - L * NCHUNK;
  const float* W = (L == 0) ? w0 : ((L == 1) ? w1 : w2);
  const int fk = (L == 0) ? 39 : 64;
  const int tid = threadIdx.x;

  for (int e = tid; e < 4096; e += 256) {     // coalesced fp32 read
    int kc = e >> 7, n = e & 127;
    int kidx = c * 32 + kc;
    int h = kidx >> 6, k = kidx & 63;
    float v = (k < fk) ? W[(h * fk + k) * SN + n] : 0.0f;
    T[kc * 132 + n] = v;
  }
  __syncthreads();
  uint32_t* dst32 = (uint32_t*)(wout + (size_t)bc * CHUNK_ELEMS);
  for (int e = tid; e < 2048; e += 256) {     // packed u32 writes, [n][k] order
    int n = e >> 4, i = e & 15;
    uint32_t lo = f2bf(T[(2 * i) * 132 + n]);
    uint32_t hi = f2bf(T[(2 * i + 1) * 132 + n]);
    dst32[n * (WROW / 2) + i] = lo | (hi << 16);
  }
}

// ---------------- fused main kernel ----------------
// 256 blocks x 512 threads (8 waves), 1 block/CU, 2 waves/SIMD.
// Block owns 8 batches (M=128 rows, m = bl*16+d). Waves: kpar = wave>>2
// (K-split by chunk parity), widx = wave&3 -> wm=(widx&1)*64, wn=(widx>>1)*64.
// 64x64 wave tile, acc 4x4 (R1-verified data paths). Per step, group (c&1)
// computes chunk c; the OTHER group issues the async staging of chunk c+1.
// Partials combined pre-ReLU through WS[1] (8 KB window, f32, exact).
__global__ __launch_bounds__(512, 2) void cin_main(
    const float* __restrict__ x,       // (2048, 39, 16) fp32
    const float* __restrict__ bias0, const float* __restrict__ bias1,
    const float* __restrict__ bias2,
    const uint16_t* __restrict__ wblk, // blocked bf16 weights (d_ws)
    float* __restrict__ out) {         // (2048, 256) fp32

  __shared__ __align__(16) uint16_t X0[128 * XROW];     // bf16 x0[m][h], h<39, rest 0
  __shared__ __align__(16) uint16_t XK[128 * XROW];     // bf16 xk[m][k], k<64
  __shared__ __align__(16) uint16_t WS[2][CHUNK_ELEMS]; // double-buffered W chunk

  const int tid  = threadIdx.x;
  const int lane = tid & 63;
  const int wave = tid >> 6;
  const int l16  = lane & 15;
  const int quad = lane >> 4;
  const int kpar = wave >> 2;          // SIMD i hosts wave i (kpar0) + wave i+4 (kpar1)
  const int widx = wave & 3;
  const int wm = (widx & 1) * 64;
  const int wn = (widx >> 1) * 64;
  const int bbase = blockIdx.x * 8;
  const int mtb = wm >> 4;             // 0 or 4

  // zero X0 (incl. pads; layer-0 xk cols 39..63 must be 0): 18432 B = 4608 dwords
  {
    uint32_t* p = (uint32_t*)X0;
#pragma unroll
    for (int i = 0; i < 9; i++) p[tid + 512 * i] = 0u;
  }
  __syncthreads();

  // fill X0[m = bl*16+d][h] = bf16(x[bbase+bl][h][d])  (coalesced over e)
#pragma unroll
  for (int it = 0; it < 10; ++it) {
    int e = tid + it * 512;            // e = bl*624 + h*16 + d, 8*624 = 4992 total
    if (e < 8 * F0N * DN) {
      float v = x[(size_t)bbase * (F0N * DN) + e];
      int d = e & 15, p = e >> 4;
      int bl = p / F0N, h = p - bl * F0N;
      X0[(bl * 16 + d) * XROW + h] = f2bf(v);
    }
  }

  // loop-invariant lane offsets (uint16 units) — R1/R3 forms
  int x0row[4], akoff[4], boff[4];
#pragma unroll
  for (int i = 0; i < 4; i++) {
    x0row[i] = (wm + i * 16 + l16) * XROW;             // scalar h-reads
    akoff[i] = x0row[i] + quad * 8;                    // xk vec reads (+k2)
    boff[i]  = (wn + i * 16 + l16) * WROW + quad * 8;  // W reads
  }

  // prologue: stage layer-0 chunk 0 into WS[0] (kpar1 group: 256 lanes, 640 loads)
  if (kpar == 1) {
    const int t4 = widx * 64 + lane;   // 0..255
#pragma unroll
    for (int it = 0; it < 3; it++) {
      int i = t4 + it * 256;
      if (i < 640) load16_lds(wblk + i * 8, ((uint16_t*)WS[0]) + i * 8);
    }
  }

#pragma unroll 1
  for (int L = 0; L < 3; L++) {
    const uint16_t* xk16 = (L == 0) ? X0 : XK;
    floatx4 acc[4][4] = {};

#pragma unroll 1
    for (int c = 0; c < NCHUNK; c++) {
      // single barrier per step: drains stage(c) (vmcnt) + LDS, syncs all 8 waves
      __syncthreads();

      if (kpar != (c & 1)) {
        // idle group issues next stage (drains at next barrier)
        const int gc = L * NCHUNK + c + 1;          // parity continuous (78 even)
        if (gc < TOTCHUNK) {
          const uint16_t* g = wblk + (size_t)gc * CHUNK_ELEMS;
          uint16_t* dst = (uint16_t*)WS[(c + 1) & 1];
          const int t4 = widx * 64 + lane;
#pragma unroll
          for (int it = 0; it < 3; it++) {
            int i = t4 + it * 256;
            if (i < 640) load16_lds(g + i * 8, dst + i * 8);
          }
        }
      } else {
        // active group computes chunk c
        const int h  = c >> 1;
        const int k2 = (c & 1) << 5;
        const uint16_t* wsrc = (const uint16_t*)WS[c & 1];

        float xs[4];
#pragma unroll
        for (int mi = 0; mi < 4; mi++) xs[mi] = bf2f(X0[x0row[mi] + h]);

        short8 bfr[4];
#pragma unroll
        for (int ni = 0; ni < 4; ni++)
          bfr[ni] = *(const short8*)(wsrc + boff[ni]);   // B[n][k=quad*8+j]

        short8 afr[4];
#pragma unroll
        for (int mi = 0; mi < 4; mi++) {
          uint4v w = *(const uint4v*)(xk16 + akoff[mi] + k2);  // 8 bf16 of xk
          const float s = xs[mi];
          uint32_t rr[4];
#pragma unroll
          for (int t = 0; t < 4; t++) {
            uint32_t wv = (t == 0) ? w.x : (t == 1) ? w.y : (t == 2) ? w.z : w.w;
            float lo = __uint_as_float(wv << 16) * s;          // even k
            float hi = __uint_as_float(wv & 0xffff0000u) * s;  // odd k
            rr[t] = __builtin_amdgcn_perm(__float_as_uint(hi), __float_as_uint(lo),
                                          0x07060302u);        // truncating pack
          }
          uint4v av = {rr[0], rr[1], rr[2], rr[3]};
          afr[mi] = __builtin_bit_cast(short8, av);            // A[m=l16][k=quad*8+j]
        }

#pragma unroll
        for (int mi = 0; mi < 4; mi++)
#pragma unroll
          for (int ni = 0; ni < 4; ni++)
            acc[mi][ni] = __builtin_amdgcn_mfma_f32_16x16x32_bf16(
                afr[mi], bfr[ni], acc[mi][ni], 0, 0, 0);
      }
    } // chunk loop

    __syncthreads();  // chunk-77 reads done; WS[1] now free (next-layer stage -> WS[0])

    // ---- combine partials (pre-ReLU, f32, exact): kpar1 -> WS[1] window -> kpar0 ----
    {
      floatx4* exv = (floatx4*)WS[1];   // 8192 B window: [widx][fi][lane] of floatx4
#pragma unroll 1
      for (int s = 0; s < 8; s++) {
        const int mi = s >> 1, nb = (s & 1) * 2;
        if (kpar == 1) {
#pragma unroll
          for (int fi = 0; fi < 2; fi++)
            exv[widx * 128 + fi * 64 + lane] = acc[mi][nb + fi];
        }
        __syncthreads();
        if (kpar == 0) {
#pragma unroll
          for (int fi = 0; fi < 2; fi++) {
            floatx4 p = exv[widx * 128 + fi * 64 + lane];
            acc[mi][nb + fi] += p;
          }
        }
        __syncthreads();   // before kpar1 overwrites window
      }
    }

    // ---- epilogue (combined accs live in kpar0): bias+relu, d-sum, xk handoff ----
    if (kpar == 0) {
      const float* bp = (L == 0) ? bias0 : ((L == 1) ? bias1 : bias2);
      float bv[4];
#pragma unroll
      for (int ni = 0; ni < 4; ni++) bv[ni] = bp[wn + ni * 16 + l16];

      // C/D layout: D[m = quad*4+reg][n = l16]; m-tile rows = 16 d's of batch bl
      if (L == 2 || wn == 64) {          // direct-output columns
#pragma unroll
        for (int mi = 0; mi < 4; mi++) {
          const int bl = mtb + mi;
#pragma unroll
          for (int ni = 0; ni < 4; ni++) {
            float sacc = 0.f;
#pragma unroll
            for (int r = 0; r < 4; r++) sacc += fmaxf(acc[mi][ni][r] + bv[ni], 0.f);
            sacc += __shfl_xor(sacc, 16);  // reduce over quad -> sum over 16 d
            sacc += __shfl_xor(sacc, 32);
            if (quad == 0) {
              // concat: L0 s64:128 -> 0:64 ; L1 s64:128 -> 64:128 ; L2 s -> 128:256
              int col = (L == 2) ? (128 + wn + ni * 16 + l16) : (L * 64 + ni * 16 + l16);
              out[(size_t)(bbase + bl) * 256 + col] = sacc;
            }
          }
        }
      }
      if (L < 2 && wn == 0) {            // xk = relu(z)[:, :64]  (waves wm=0,64: all 128 m)
#pragma unroll
        for (int mi = 0; mi < 4; mi++)
#pragma unroll
          for (int ni = 0; ni < 4; ni++)
#pragma unroll
            for (int r = 0; r < 4; r++) {
              int m = wm + mi * 16 + quad * 4 + r;
              int k = ni * 16 + l16;
              float z = fmaxf(acc[mi][ni][r] + bv[ni], 0.f);
              XK[m * XROW + k] = f2bf(z);
            }
      }
    }
    // next layer's first __syncthreads orders XK writes before formation reads
  } // layer loop
}

extern "C" void kernel_launch(void* const* d_in, const int* in_sizes, int n_in,
                              void* d_out, int out_size, void* d_ws, size_t ws_size,
                              hipStream_t stream) {
  (void)in_sizes; (void)n_in; (void)out_size; (void)ws_size;
  const float* x  = (const float*)d_in[0];
  const float* w0 = (const float*)d_in[1];
  const float* b0 = (const float*)d_in[2];
  const float* w1 = (const float*)d_in[3];
  const float* b1 = (const float*)d_in[4];
  const float* w2 = (const float*)d_in[5];
  const float* b2 = (const float*)d_in[6];
  uint16_t* wblk  = (uint16_t*)d_ws;   // 234 * 5120 * 2 = 2,396,160 B

  cin_prepass<<<TOTCHUNK, 256, 0, stream>>>(w0, w1, w2, wblk);
  cin_main<<<256, 512, 0, stream>>>(x, b0, b1, b2, wblk, (float*)d_out);
}

// Round 5
// 199.270 us; speedup vs baseline: 7.4781x; 7.4781x over previous
//
#include <hip/hip_runtime.h>
#include <stdint.h>
#include <stddef.h>

// ---------------- problem constants ----------------
// B=2048, F0=39, D=16, layers 128/128/128, xk halves to 64 after each layer.
// GEMM view: M=(b,d), N=s=128, K=(h,k) padded to 39*64=2496 for all layers.
#define F0N    39
#define DN     16
#define SN     128
#define NCHUNK 78                      // 2496 / 32
#define WROW   40                      // bf16 per staged-W row: 32 + 8 pad (80B, 16B-aligned)
#define XROW   72                      // bf16 per X0/XK row: 64 + 8 pad (144B, 16B-aligned)
#define CHUNK_ELEMS (SN * WROW)        // 5120 bf16 = 10240 B per staged chunk
#define PER_LAYER_ELEMS (NCHUNK * CHUNK_ELEMS)
#define TOTCHUNK 234                   // 3 * 78

typedef __attribute__((ext_vector_type(8))) short short8;   // MFMA A/B operand
typedef __attribute__((ext_vector_type(4))) float floatx4;  // MFMA accumulator
typedef __attribute__((ext_vector_type(4))) uint32_t uint4v;

__device__ __forceinline__ uint16_t f2bf(float f) {         // RNE f32->bf16
  uint32_t u = __float_as_uint(f);
  u += 0x7fffu + ((u >> 16) & 1u);
  return (uint16_t)(u >> 16);
}
__device__ __forceinline__ float bf2f(uint16_t b) {
  return __uint_as_float(((uint32_t)b) << 16);
}

// async global->LDS, 16B per lane (wave-uniform base + lane*16 pattern)
__device__ __forceinline__ void load16_lds(const void* g, void* l) {
  __builtin_amdgcn_global_load_lds(
      (__attribute__((address_space(1))) uint32_t*)(uintptr_t)g,
      (__attribute__((address_space(3))) uint32_t*)(uint32_t)(uintptr_t)l,
      16, 0, 0);
}

// ---------------- pre-pass: W fp32 -> bf16, [n][k] layout (R3-verified) ----------------
__global__ __launch_bounds__(256) void cin_prepass(
    const float* __restrict__ w0, const float* __restrict__ w1,
    const float* __restrict__ w2, uint16_t* __restrict__ wout) {
  __shared__ float T[32 * 132];               // [k_in_chunk][n], +4 pad floats per row
  const int bc = blockIdx.x;                  // 0..233
  const int L = bc / NCHUNK;
  const int c = bc - L * NCHUNK;
  const float* W = (L == 0) ? w0 : ((L == 1) ? w1 : w2);
  const int fk = (L == 0) ? 39 : 64;
  const int tid = threadIdx.x;

  for (int e = tid; e < 4096; e += 256) {     // coalesced fp32 read
    int kc = e >> 7, n = e & 127;
    int kidx = c * 32 + kc;
    int h = kidx >> 6, k = kidx & 63;
    float v = (k < fk) ? W[(h * fk + k) * SN + n] : 0.0f;
    T[kc * 132 + n] = v;
  }
  __syncthreads();
  uint32_t* dst32 = (uint32_t*)(wout + (size_t)bc * CHUNK_ELEMS);
  for (int e = tid; e < 2048; e += 256) {     // packed u32 writes, [n][k] order
    int n = e >> 4, i = e & 15;
    uint32_t lo = f2bf(T[(2 * i) * 132 + n]);
    uint32_t hi = f2bf(T[(2 * i + 1) * 132 + n]);
    dst32[n * (WROW / 2) + i] = lo | (hi << 16);
  }
}

// ---------------- fused main kernel ----------------
// 256 blocks x 512 threads (8 waves), 1 block/CU, 2 waves/SIMD.
// Block owns 8 batches (M=128 rows, m = bl*16+d). Waves: kpar = wave>>2
// (K-split by chunk parity), widx = wave&3 -> wm=(widx&1)*64, wn=(widx>>1)*64.
// 64x64 wave tile, acc 4x4. Per step, group (c&1) computes chunk c; the
// OTHER group issues the async staging of chunk c+1. Partials combined
// pre-ReLU through WS[1] (8 KB window, f32). ALL acc indexing compile-time
// (R4 bug: runtime-indexed acc -> scratch -> 4.9 GB HBM spill traffic).
__global__ __launch_bounds__(512, 2) void cin_main(
    const float* __restrict__ x,       // (2048, 39, 16) fp32
    const float* __restrict__ bias0, const float* __restrict__ bias1,
    const float* __restrict__ bias2,
    const uint16_t* __restrict__ wblk, // blocked bf16 weights (d_ws)
    float* __restrict__ out) {         // (2048, 256) fp32

  __shared__ __align__(16) uint16_t X0[128 * XROW];     // bf16 x0[m][h], h<39, rest 0
  __shared__ __align__(16) uint16_t XK[128 * XROW];     // bf16 xk[m][k], k<64
  __shared__ __align__(16) uint16_t WS[2][CHUNK_ELEMS]; // double-buffered W chunk

  const int tid  = threadIdx.x;
  const int lane = tid & 63;
  const int wave = tid >> 6;
  const int l16  = lane & 15;
  const int quad = lane >> 4;
  const int kpar = wave >> 2;          // SIMD i hosts wave i (kpar0) + wave i+4 (kpar1)
  const int widx = wave & 3;
  const int wm = (widx & 1) * 64;
  const int wn = (widx >> 1) * 64;
  const int bbase = blockIdx.x * 8;
  const int mtb = wm >> 4;             // 0 or 4

  // zero X0 (incl. pads; layer-0 xk cols 39..63 must be 0): 18432 B = 4608 dwords
  {
    uint32_t* p = (uint32_t*)X0;
#pragma unroll
    for (int i = 0; i < 9; i++) p[tid + 512 * i] = 0u;
  }
  __syncthreads();

  // fill X0[m = bl*16+d][h] = bf16(x[bbase+bl][h][d])  (coalesced over e)
#pragma unroll
  for (int it = 0; it < 10; ++it) {
    int e = tid + it * 512;            // e = bl*624 + h*16 + d, 8*624 = 4992 total
    if (e < 8 * F0N * DN) {
      float v = x[(size_t)bbase * (F0N * DN) + e];
      int d = e & 15, p = e >> 4;
      int bl = p / F0N, h = p - bl * F0N;
      X0[(bl * 16 + d) * XROW + h] = f2bf(v);
    }
  }

  // loop-invariant lane offsets (uint16 units) — R1/R3 forms
  int x0row[4], akoff[4], boff[4];
#pragma unroll
  for (int i = 0; i < 4; i++) {
    x0row[i] = (wm + i * 16 + l16) * XROW;             // scalar h-reads
    akoff[i] = x0row[i] + quad * 8;                    // xk vec reads (+k2)
    boff[i]  = (wn + i * 16 + l16) * WROW + quad * 8;  // W reads
  }

  // prologue: stage layer-0 chunk 0 into WS[0] (kpar1 group: 256 lanes, 640 loads)
  if (kpar == 1) {
    const int t4 = widx * 64 + lane;   // 0..255
#pragma unroll
    for (int it = 0; it < 3; it++) {
      int i = t4 + it * 256;
      if (i < 640) load16_lds(wblk + i * 8, ((uint16_t*)WS[0]) + i * 8);
    }
  }

#pragma unroll 1
  for (int L = 0; L < 3; L++) {
    const uint16_t* xk16 = (L == 0) ? X0 : XK;
    floatx4 acc[4][4] = {};

#pragma unroll 1
    for (int c = 0; c < NCHUNK; c++) {
      // single barrier per step: drains stage(c) (vmcnt) + LDS, syncs all 8 waves
      __syncthreads();

      if (kpar != (c & 1)) {
        // idle group issues next stage (drains at next barrier)
        const int gc = L * NCHUNK + c + 1;          // parity continuous (78 even)
        if (gc < TOTCHUNK) {
          const uint16_t* g = wblk + (size_t)gc * CHUNK_ELEMS;
          uint16_t* dst = (uint16_t*)WS[(c + 1) & 1];
          const int t4 = widx * 64 + lane;
#pragma unroll
          for (int it = 0; it < 3; it++) {
            int i = t4 + it * 256;
            if (i < 640) load16_lds(g + i * 8, dst + i * 8);
          }
        }
      } else {
        // active group computes chunk c
        const int h  = c >> 1;
        const int k2 = (c & 1) << 5;
        const uint16_t* wsrc = (const uint16_t*)WS[c & 1];

        float xs[4];
#pragma unroll
        for (int mi = 0; mi < 4; mi++) xs[mi] = bf2f(X0[x0row[mi] + h]);

        short8 bfr[4];
#pragma unroll
        for (int ni = 0; ni < 4; ni++)
          bfr[ni] = *(const short8*)(wsrc + boff[ni]);   // B[n][k=quad*8+j]

        short8 afr[4];
#pragma unroll
        for (int mi = 0; mi < 4; mi++) {
          uint4v w = *(const uint4v*)(xk16 + akoff[mi] + k2);  // 8 bf16 of xk
          const float s = xs[mi];
          uint32_t rr[4];
#pragma unroll
          for (int t = 0; t < 4; t++) {
            uint32_t wv = (t == 0) ? w.x : (t == 1) ? w.y : (t == 2) ? w.z : w.w;
            float lo = __uint_as_float(wv << 16) * s;          // even k
            float hi = __uint_as_float(wv & 0xffff0000u) * s;  // odd k
            rr[t] = __builtin_amdgcn_perm(__float_as_uint(hi), __float_as_uint(lo),
                                          0x07060302u);        // truncating pack
          }
          uint4v av = {rr[0], rr[1], rr[2], rr[3]};
          afr[mi] = __builtin_bit_cast(short8, av);            // A[m=l16][k=quad*8+j]
        }

#pragma unroll
        for (int mi = 0; mi < 4; mi++)
#pragma unroll
          for (int ni = 0; ni < 4; ni++)
            acc[mi][ni] = __builtin_amdgcn_mfma_f32_16x16x32_bf16(
                afr[mi], bfr[ni], acc[mi][ni], 0, 0, 0);
      }
    } // chunk loop

    __syncthreads();  // chunk-77 reads done; WS[1] now free (next-layer stage -> WS[0])

    // ---- combine partials (pre-ReLU, f32): kpar1 -> WS[1] window -> kpar0 ----
    // FULLY UNROLLED: all acc indices compile-time so acc stays in registers.
    {
      floatx4* exv = (floatx4*)WS[1];   // 8192 B window: [widx][fi][lane] of floatx4
#pragma unroll
      for (int s = 0; s < 8; s++) {
        const int mi = s >> 1, nb = (s & 1) * 2;
        if (kpar == 1) {
          exv[widx * 128 + lane]      = acc[mi][nb];
          exv[widx * 128 + 64 + lane] = acc[mi][nb + 1];
        }
        __syncthreads();
        if (kpar == 0) {
          floatx4 p0 = exv[widx * 128 + lane];
          floatx4 p1 = exv[widx * 128 + 64 + lane];
          acc[mi][nb]     += p0;
          acc[mi][nb + 1] += p1;
        }
        __syncthreads();   // before kpar1 overwrites window
      }
    }

    // ---- epilogue (combined accs live in kpar0): bias+relu, d-sum, xk handoff ----
    if (kpar == 0) {
      const float* bp = (L == 0) ? bias0 : ((L == 1) ? bias1 : bias2);
      float bv[4];
#pragma unroll
      for (int ni = 0; ni < 4; ni++) bv[ni] = bp[wn + ni * 16 + l16];

      // C/D layout: D[m = quad*4+reg][n = l16]; m-tile rows = 16 d's of batch bl
      if (L == 2 || wn == 64) {          // direct-output columns
#pragma unroll
        for (int mi = 0; mi < 4; mi++) {
          const int bl = mtb + mi;
#pragma unroll
          for (int ni = 0; ni < 4; ni++) {
            float sacc = 0.f;
#pragma unroll
            for (int r = 0; r < 4; r++) sacc += fmaxf(acc[mi][ni][r] + bv[ni], 0.f);
            sacc += __shfl_xor(sacc, 16);  // reduce over quad -> sum over 16 d
            sacc += __shfl_xor(sacc, 32);
            if (quad == 0) {
              // concat: L0 s64:128 -> 0:64 ; L1 s64:128 -> 64:128 ; L2 s -> 128:256
              int col = (L == 2) ? (128 + wn + ni * 16 + l16) : (L * 64 + ni * 16 + l16);
              out[(size_t)(bbase + bl) * 256 + col] = sacc;
            }
          }
        }
      }
      if (L < 2 && wn == 0) {            // xk = relu(z)[:, :64]  (waves wm=0,64: all 128 m)
#pragma unroll
        for (int mi = 0; mi < 4; mi++)
#pragma unroll
          for (int ni = 0; ni < 4; ni++)
#pragma unroll
            for (int r = 0; r < 4; r++) {
              int m = wm + mi * 16 + quad * 4 + r;
              int k = ni * 16 + l16;
              float z = fmaxf(acc[mi][ni][r] + bv[ni], 0.f);
              XK[m * XROW + k] = f2bf(z);
            }
      }
    }
    // next layer's first __syncthreads orders XK writes before formation reads
  } // layer loop
}

extern "C" void kernel_launch(void* const* d_in, const int* in_sizes, int n_in,
                              void* d_out, int out_size, void* d_ws, size_t ws_size,
                              hipStream_t stream) {
  (void)in_sizes; (void)n_in; (void)out_size; (void)ws_size;
  const float* x  = (const float*)d_in[0];
  const float* w0 = (const float*)d_in[1];
  const float* b0 = (const float*)d_in[2];
  const float* w1 = (const float*)d_in[3];
  const float* b1 = (const float*)d_in[4];
  const float* w2 = (const float*)d_in[5];
  const float* b2 = (const float*)d_in[6];
  uint16_t* wblk  = (uint16_t*)d_ws;   // 234 * 5120 * 2 = 2,396,160 B

  cin_prepass<<<TOTCHUNK, 256, 0, stream>>>(w0, w1, w2, wblk);
  cin_main<<<256, 512, 0, stream>>>(x, b0, b1, b2, wblk, (float*)d_out);
}

// Round 6
// 179.130 us; speedup vs baseline: 8.3188x; 1.1124x over previous
//
#include <hip/hip_runtime.h>
#include <stdint.h>
#include <stddef.h>

// ---------------- problem constants ----------------
// B=2048, F0=39, D=16, layers 128/128/128, xk halves to 64 after each layer.
// Factored form: y_h[s,d] = sum_k W[h,k,s]*xk[b,k,d] (MFMA: A=W static, B=xk
// h-invariant -> register-cached per layer); z[b,s,d] = sum_h x0[b,h,d]*y_h[s,d]
// (4 fmac per (b,h), x0 in full f32).
#define F0N  39
#define SN   128
#define X0TS 44            // f32 stride of X0T row (b,d): 39+pad, 16B-aligned, 2-way banks
#define XKTS 72            // u16 stride of XKT row (b,d): 64+8 pad, 16B-aligned
#define WBLK 8192          // u16 per (L,h) W block: 8 s-tiles x 2 chunks x 512
#define NHB  117           // 3*39 prepass blocks

typedef __attribute__((ext_vector_type(8))) short short8;   // MFMA A/B operand
typedef __attribute__((ext_vector_type(4))) float floatx4;  // MFMA accumulator

__device__ __forceinline__ uint16_t f2bf(float f) {         // RNE f32->bf16
  uint32_t u = __float_as_uint(f);
  u += 0x7fffu + ((u >> 16) & 1u);
  return (uint16_t)(u >> 16);
}

// async global->LDS, 16B per lane (wave-uniform base + lane*16 pattern)
__device__ __forceinline__ void load16_lds(const void* g, void* l) {
  __builtin_amdgcn_global_load_lds(
      (__attribute__((address_space(1))) uint32_t*)(uintptr_t)g,
      (__attribute__((address_space(3))) uint32_t*)(uint32_t)(uintptr_t)l,
      16, 0, 0);
}

// ---------------- pre-pass: W fp32 -> bf16 A-fragment blocks ----------------
// One block per (L,h). Block layout (u16 idx in 8192):
//   (st*2+ch)*512 + lane*8 + j  where value = W[h][k=ch*32+quad*8+j][s=st*16+l16]
// A-frag convention (R1/R3/R5-verified): operand0 = [own-dim=l16][k=quad*8+j].
__global__ __launch_bounds__(256) void cin_prepass(
    const float* __restrict__ w0, const float* __restrict__ w1,
    const float* __restrict__ w2, uint16_t* __restrict__ wt) {
  __shared__ float T[64 * 132];               // [k][s], +4 pad floats per row
  const int bc = blockIdx.x;                  // 0..116
  const int L = bc / F0N;
  const int h = bc - L * F0N;
  const float* W = (L == 0) ? w0 : ((L == 1) ? w1 : w2);
  const int fk = (L == 0) ? 39 : 64;
  const int tid = threadIdx.x;

  for (int e = tid; e < 8192; e += 256) {     // coalesced fp32 read, k padded to 64
    int k = e >> 7, s = e & 127;
    T[k * 132 + s] = (k < fk) ? W[(h * fk + k) * SN + s] : 0.0f;
  }
  __syncthreads();
  uint32_t* dst = (uint32_t*)(wt + (size_t)bc * WBLK);
  for (int i = tid; i < 4096; i += 256) {     // coalesced u32 writes, frag order
    int frag = i >> 8, w = i & 255;
    int st = frag >> 1, ch = frag & 1;
    int ln = w >> 2, jp = w & 3;
    int quad = ln >> 4, l16 = ln & 15;
    int k0 = ch * 32 + quad * 8 + jp * 2;
    int s = st * 16 + l16;
    dst[i] = (uint32_t)f2bf(T[k0 * 132 + s]) | ((uint32_t)f2bf(T[(k0 + 1) * 132 + s]) << 16);
  }
}

// ---------------- fused main kernel ----------------
// 256 blocks x 512 threads (8 waves), 1 block/CU, 2 waves/SIMD.
// Block owns 8 batches. Wave st owns s-tile [st*16, st*16+16) x all 8 b.
// Per (L): Bf (xk B-frags) register-cached (h-invariant!); per h: stage W block
// (16 KB) double-buffered, 2 LDS W-frag reads, 8x2 MFMA, 8x4 fmac (x0 f32).
// D-layout: D[s=st*16+quad*4+r][d=l16]; sum_d = shfl_xor over l16 bits.
__global__ __launch_bounds__(512, 2) void cin_main(
    const float* __restrict__ x,       // (2048, 39, 16) fp32
    const float* __restrict__ bias0, const float* __restrict__ bias1,
    const float* __restrict__ bias2,
    const uint16_t* __restrict__ wt,   // A-frag bf16 weights (d_ws)
    float* __restrict__ out) {         // (2048, 256) fp32

  __shared__ __align__(16) float    X0T[8 * 16 * X0TS];   // x0[b][d][h] f32, 22528 B
  __shared__ __align__(16) uint16_t XKT[8 * 16 * XKTS];   // xk[b][d][k] bf16, 18432 B
  __shared__ __align__(16) uint16_t WS[2][WBLK];          // double-buffered W, 32768 B

  const int tid  = threadIdx.x;
  const int lane = tid & 63;
  const int st   = tid >> 6;           // wave index = s-tile
  const int l16  = lane & 15;          // = d (output col)
  const int quad = lane >> 4;
  const int bbase = blockIdx.x * 8;

  // zero X0T (h-pad 39..43 must be 0) and XKT
  {
    float* p = X0T;
#pragma unroll
    for (int i = 0; i < 11; i++) p[tid + 512 * i] = 0.f;   // 11*512 = 5632 ✓
    uint32_t* q = (uint32_t*)XKT;
#pragma unroll
    for (int i = 0; i < 9; i++) q[tid + 512 * i] = 0u;     // 9*512 = 4608 ✓
  }
  __syncthreads();

  // fill X0T[b][d][h] = x[bbase+b][h][d]  (coalesced read, LDS transpose-scatter)
#pragma unroll
  for (int it = 0; it < 10; ++it) {
    int e = tid + it * 512;            // e = (b*39 + h)*16 + d, total 4992
    if (e < 8 * F0N * 16) {
      float v = x[(size_t)bbase * (F0N * 16) + e];
      int d = e & 15, p = e >> 4;
      int b = p / F0N, h = p - b * F0N;
      X0T[(b * 16 + d) * X0TS + h] = v;
    }
  }
  __syncthreads();

  // build layer-0 XKT[b][d][k] = bf16(x0[b][k][d]) for k<39, 0 for k in [39,64)
  {
    int b = tid >> 6, d = (tid >> 2) & 15, kg = tid & 3;
    const float* src = &X0T[(b * 16 + d) * X0TS];
    uint32_t* drow = (uint32_t*)&XKT[(b * 16 + d) * XKTS + kg * 16];
#pragma unroll
    for (int i2 = 0; i2 < 8; i2++) {
      int k0 = kg * 16 + i2 * 2;
      uint32_t lo = (k0 < 39)     ? (uint32_t)f2bf(src[k0])     : 0u;
      uint32_t hi = (k0 + 1 < 39) ? (uint32_t)f2bf(src[k0 + 1]) : 0u;
      drow[i2] = lo | (hi << 16);
    }
  }

  // prologue: stage (L0,h0) W block into WS[0]
  load16_lds(wt + tid * 8,         ((uint16_t*)WS[0]) + tid * 8);
  load16_lds(wt + (tid + 512) * 8, ((uint16_t*)WS[0]) + (tid + 512) * 8);
  __syncthreads();   // XKT build visible for Bf loads

#pragma unroll 1
  for (int L = 0; L < 3; ++L) {
    // register-cache B-fragments (h-invariant within layer!)
    short8 Bf0[8], Bf1[8];
#pragma unroll
    for (int b = 0; b < 8; ++b) {
      const uint16_t* r = XKT + (b * 16 + l16) * XKTS + quad * 8;
      Bf0[b] = *(const short8*)r;          // k 0..31 chunk
      Bf1[b] = *(const short8*)(r + 32);   // k 32..63 chunk
    }
    const float* bp = (L == 0) ? bias0 : ((L == 1) ? bias1 : bias2);
    float bvr[4];
#pragma unroll
    for (int r = 0; r < 4; ++r) bvr[r] = bp[st * 16 + quad * 4 + r];

    floatx4 z[8] = {};
    const floatx4 zero4 = {0.f, 0.f, 0.f, 0.f};

#pragma unroll 1
    for (int h4 = 0; h4 < 10; ++h4) {
      float4 xv[8];                        // x0 for h4*4 .. h4*4+3 (h=39.. are 0-pads)
#pragma unroll
      for (int b = 0; b < 8; ++b)
        xv[b] = *(const float4*)&X0T[(b * 16 + l16) * X0TS + h4 * 4];

#pragma unroll
      for (int hi = 0; hi < 4; ++hi) {
        const int h  = h4 * 4 + hi;
        const int gh = L * 40 + h;         // gh&1 == hi&1 (L*40, h4*4 even)
        __syncthreads();                   // drains stage(gh); WS[hi&1] ready

        if (gh < 119) {                    // stage next W block
          int hn = h + 1, Ln = L;
          if (hn == 40) { Ln = L + 1; hn = 0; }
          int hc = (hn > 38) ? 38 : hn;    // h=39 is x0=0 pad: restage h=38 (unused)
          const uint16_t* g = wt + (size_t)(Ln * F0N + hc) * WBLK;
          uint16_t* dst = (uint16_t*)WS[(hi + 1) & 1];
          load16_lds(g + tid * 8,         dst + tid * 8);
          load16_lds(g + (tid + 512) * 8, dst + (tid + 512) * 8);
        }

        const uint16_t* wsrc = (const uint16_t*)WS[hi & 1];
        short8 Wf0 = *(const short8*)(wsrc + (st * 2 + 0) * 512 + lane * 8);
        short8 Wf1 = *(const short8*)(wsrc + (st * 2 + 1) * 512 + lane * 8);

#pragma unroll
        for (int b = 0; b < 8; ++b) {
          floatx4 y = __builtin_amdgcn_mfma_f32_16x16x32_bf16(Wf0, Bf0[b], zero4, 0, 0, 0);
          y = __builtin_amdgcn_mfma_f32_16x16x32_bf16(Wf1, Bf1[b], y, 0, 0, 0);
          const float xs = (hi == 0) ? xv[b].x : (hi == 1) ? xv[b].y
                         : (hi == 2) ? xv[b].z : xv[b].w;
#pragma unroll
          for (int r = 0; r < 4; ++r) z[b][r] += xs * y[r];
        }
      }
    }

    // ---- epilogue: bias+relu; xk handoff; sum_d (over l16) -> out ----
#pragma unroll
    for (int b = 0; b < 8; ++b) {
#pragma unroll
      for (int r = 0; r < 4; ++r) {
        float t = fmaxf(z[b][r] + bvr[r], 0.f);
        if (L < 2 && st < 4)               // xk = relu(z)[:, :64]; k = s < 64
          XKT[(b * 16 + l16) * XKTS + st * 16 + quad * 4 + r] = f2bf(t);
        float s4 = t;                       // reduce over d = l16 (bits 0..3)
        s4 += __shfl_xor(s4, 1);
        s4 += __shfl_xor(s4, 2);
        s4 += __shfl_xor(s4, 4);
        s4 += __shfl_xor(s4, 8);
        if (l16 == 0) {
          int s = st * 16 + quad * 4 + r;
          // concat: L0 s64:128 -> 0:64 ; L1 s64:128 -> 64:128 ; L2 s -> 128:256
          if (L == 2)      out[(size_t)(bbase + b) * 256 + 128 + s] = s4;
          else if (s >= 64) out[(size_t)(bbase + b) * 256 + L * 64 + (s - 64)] = s4;
        }
      }
    }
    __syncthreads();   // handoff writes visible before next-layer Bf loads
  }
}

extern "C" void kernel_launch(void* const* d_in, const int* in_sizes, int n_in,
                              void* d_out, int out_size, void* d_ws, size_t ws_size,
                              hipStream_t stream) {
  (void)in_sizes; (void)n_in; (void)out_size; (void)ws_size;
  const float* x  = (const float*)d_in[0];
  const float* w0 = (const float*)d_in[1];
  const float* b0 = (const float*)d_in[2];
  const float* w1 = (const float*)d_in[3];
  const float* b1 = (const float*)d_in[4];
  const float* w2 = (const float*)d_in[5];
  const float* b2 = (const float*)d_in[6];
  uint16_t* wt    = (uint16_t*)d_ws;   // 117 * 8192 * 2 = 1,916,928 B

  cin_prepass<<<NHB, 256, 0, stream>>>(w0, w1, w2, wt);
  cin_main<<<256, 512, 0, stream>>>(x, b0, b1, b2, wt, (float*)d_out);
}

// Round 7
// 147.537 us; speedup vs baseline: 10.1002x; 1.2141x over previous
//
#include <hip/hip_runtime.h>
#include <stdint.h>
#include <stddef.h>

// ---------------- problem constants ----------------
// B=2048, F0=39, D=16, layers 128/128/128, xk halves to 64 after each layer.
// Factored form: y_h[s,d] = sum_k W[h,k,s]*xk[b,k,d] (MFMA: A=W static, B=xk
// h-invariant -> register-cached per layer); z[b,s,d] = sum_h x0[b,h,d]*y_h[s,d]
// (4 fmac per (b,h), x0 in full f32). R7: W fragments loaded per-wave straight
// from global (fragment-order wt, L2-resident) with distance-1 register
// prefetch -> ZERO barriers in the h-loop (R6 lost ~1900 cyc/step to the
// __syncthreads + vmcnt(0) drain of the 16 KB global_load_lds stage).
#define F0N  39
#define SN   128
#define X0TS 44            // f32 stride of X0T row (b,d): 39+pad, 16B-aligned
#define XKTS 72            // u16 stride of XKT row (b,d): 64+8 pad, 16B-aligned
#define WBLK 8192          // u16 per (L,h) W block: 8 s-tiles x 2 chunks x 512
#define NHB  117           // 3*39 prepass blocks

typedef __attribute__((ext_vector_type(8))) short short8;   // MFMA A/B operand
typedef __attribute__((ext_vector_type(4))) float floatx4;  // MFMA accumulator

__device__ __forceinline__ uint16_t f2bf(float f) {         // RNE f32->bf16
  uint32_t u = __float_as_uint(f);
  u += 0x7fffu + ((u >> 16) & 1u);
  return (uint16_t)(u >> 16);
}

// ---------------- pre-pass: W fp32 -> bf16 A-fragment blocks (R6-verified) ----------------
// One block per (L,h). Block layout (u16 idx in 8192):
//   (st*2+ch)*512 + lane*8 + j  where value = W[h][k=ch*32+quad*8+j][s=st*16+l16]
__global__ __launch_bounds__(256) void cin_prepass(
    const float* __restrict__ w0, const float* __restrict__ w1,
    const float* __restrict__ w2, uint16_t* __restrict__ wt) {
  __shared__ float T[64 * 132];               // [k][s], +4 pad floats per row
  const int bc = blockIdx.x;                  // 0..116
  const int L = bc / F0N;
  const int h = bc - L * F0N;
  const float* W = (L == 0) ? w0 : ((L == 1) ? w1 : w2);
  const int fk = (L == 0) ? 39 : 64;
  const int tid = threadIdx.x;

  for (int e = tid; e < 8192; e += 256) {     // coalesced fp32 read, k padded to 64
    int k = e >> 7, s = e & 127;
    T[k * 132 + s] = (k < fk) ? W[(h * fk + k) * SN + s] : 0.0f;
  }
  __syncthreads();
  uint32_t* dst = (uint32_t*)(wt + (size_t)bc * WBLK);
  for (int i = tid; i < 4096; i += 256) {     // coalesced u32 writes, frag order
    int frag = i >> 8, w = i & 255;
    int st = frag >> 1, ch = frag & 1;
    int ln = w >> 2, jp = w & 3;
    int quad = ln >> 4, l16 = ln & 15;
    int k0 = ch * 32 + quad * 8 + jp * 2;
    int s = st * 16 + l16;
    dst[i] = (uint32_t)f2bf(T[k0 * 132 + s]) | ((uint32_t)f2bf(T[(k0 + 1) * 132 + s]) << 16);
  }
}

// ---------------- fused main kernel ----------------
// 256 blocks x 512 threads (8 waves), 1 block/CU. Block owns 8 batches.
// Wave st owns s-tile [st*16, st*16+16) x all 8 b. Per layer: Bf (xk B-frags)
// register-cached; per h: 2 coalesced global W-frag loads (dist-1 prefetch),
// 8 ds_read_b32 (x0), 16 MFMA, 32 fmac. NO barriers in the h-loop.
// h loops to 40: h=39 has xs=0 (X0T pad) so its MFMA result is multiplied by
// 0; its prefetch seeds the next layer's h0.
// D-layout: D[s=st*16+quad*4+r][d=l16]; sum_d = shfl_xor over l16 bits.
__global__ __launch_bounds__(512, 2) void cin_main(
    const float* __restrict__ x,       // (2048, 39, 16) fp32
    const float* __restrict__ bias0, const float* __restrict__ bias1,
    const float* __restrict__ bias2,
    const uint16_t* __restrict__ wt,   // A-frag bf16 weights (d_ws)
    float* __restrict__ out) {         // (2048, 256) fp32

  __shared__ __align__(16) float    X0T[8 * 16 * X0TS];   // x0[b][d][h] f32, 22528 B
  __shared__ __align__(16) uint16_t XKT[8 * 16 * XKTS];   // xk[b][d][k] bf16, 18432 B

  const int tid  = threadIdx.x;
  const int lane = tid & 63;
  const int st   = tid >> 6;           // wave index = s-tile
  const int l16  = lane & 15;          // = d (output col)
  const int quad = lane >> 4;
  const int bbase = blockIdx.x * 8;

  // zero X0T (h-pad 39..43 must be 0 -> xs=0 at h=39) and XKT (k-pad for L0)
  {
    float* p = X0T;
#pragma unroll
    for (int i = 0; i < 11; i++) p[tid + 512 * i] = 0.f;   // 11*512 = 5632
    uint32_t* q = (uint32_t*)XKT;
#pragma unroll
    for (int i = 0; i < 9; i++) q[tid + 512 * i] = 0u;     // 9*512 = 4608
  }
  __syncthreads();

  // fill X0T[b][d][h] = x[bbase+b][h][d]  (coalesced read, LDS transpose-scatter)
#pragma unroll
  for (int it = 0; it < 10; ++it) {
    int e = tid + it * 512;            // e = (b*39 + h)*16 + d, total 4992
    if (e < 8 * F0N * 16) {
      float v = x[(size_t)bbase * (F0N * 16) + e];
      int d = e & 15, p = e >> 4;
      int b = p / F0N, h = p - b * F0N;
      X0T[(b * 16 + d) * X0TS + h] = v;
    }
  }
  __syncthreads();

  // build layer-0 XKT[b][d][k] = bf16(x0[b][k][d]) for k<39, 0 for k in [39,64)
  {
    int b = tid >> 6, d = (tid >> 2) & 15, kg = tid & 3;
    const float* src = &X0T[(b * 16 + d) * X0TS];
    uint32_t* drow = (uint32_t*)&XKT[(b * 16 + d) * XKTS + kg * 16];
#pragma unroll
    for (int i2 = 0; i2 < 8; i2++) {
      int k0 = kg * 16 + i2 * 2;
      uint32_t lo = (k0 < 39)     ? (uint32_t)f2bf(src[k0])     : 0u;
      uint32_t hi = (k0 + 1 < 39) ? (uint32_t)f2bf(src[k0 + 1]) : 0u;
      drow[i2] = lo | (hi << 16);
    }
  }
  __syncthreads();   // XKT build visible for Bf loads

  // per-wave global W base (u16 units): + gh*WBLK + ch*512
  const uint16_t* wlane = wt + st * 1024 + (size_t)lane * 8;
  const float*    xr    = &X0T[l16 * X0TS];    // + b*16*X0TS + h

  // seed prefetch: (L0, h0)
  short8 Wc0 = *(const short8*)(wlane);
  short8 Wc1 = *(const short8*)(wlane + 512);

#pragma unroll 1
  for (int L = 0; L < 3; ++L) {
    // register-cache B-fragments (h-invariant within layer)
    short8 Bf0[8], Bf1[8];
#pragma unroll
    for (int b = 0; b < 8; ++b) {
      const uint16_t* r = XKT + (b * 16 + l16) * XKTS + quad * 8;
      Bf0[b] = *(const short8*)r;          // k 0..31 chunk
      Bf1[b] = *(const short8*)(r + 32);   // k 32..63 chunk
    }
    const float* bp = (L == 0) ? bias0 : ((L == 1) ? bias1 : bias2);
    float bvr[4];
#pragma unroll
    for (int r = 0; r < 4; ++r) bvr[r] = bp[st * 16 + quad * 4 + r];

    floatx4 z[8] = {};
    const floatx4 zero4 = {0.f, 0.f, 0.f, 0.f};

#pragma unroll 1
    for (int h = 0; h < 40; ++h) {
      // distance-1 prefetch of next h (or next layer's h0); wave-uniform addr
      short8 Wn0, Wn1;
      {
        int Ln = L, hh = h + 1;
        if (hh >= 39) { if (L < 2) { Ln = L + 1; hh = 0; } else hh = 38; }
        const uint16_t* wl = wlane + (size_t)(Ln * F0N + hh) * WBLK;
        Wn0 = *(const short8*)wl;
        Wn1 = *(const short8*)(wl + 512);
      }

      // x0 scalars (h=39 -> 0 from pad); ds_read_b32 with immediate offsets
      float xs[8];
#pragma unroll
      for (int b = 0; b < 8; ++b) xs[b] = xr[b * 16 * X0TS + h];

#pragma unroll
      for (int b = 0; b < 8; ++b) {
        floatx4 y = __builtin_amdgcn_mfma_f32_16x16x32_bf16(Wc0, Bf0[b], zero4, 0, 0, 0);
        y = __builtin_amdgcn_mfma_f32_16x16x32_bf16(Wc1, Bf1[b], y, 0, 0, 0);
#pragma unroll
        for (int r = 0; r < 4; ++r) z[b][r] += xs[b] * y[r];
      }
      Wc0 = Wn0;
      Wc1 = Wn1;
    }

    // ---- epilogue: bias+relu; xk handoff; sum_d (over l16) -> out ----
#pragma unroll
    for (int b = 0; b < 8; ++b) {
#pragma unroll
      for (int r = 0; r < 4; ++r) {
        float t = fmaxf(z[b][r] + bvr[r], 0.f);
        if (L < 2 && st < 4)               // xk = relu(z)[:, :64]; k = s < 64
          XKT[(b * 16 + l16) * XKTS + st * 16 + quad * 4 + r] = f2bf(t);
        float s4 = t;                       // reduce over d = l16 (bits 0..3)
        s4 += __shfl_xor(s4, 1);
        s4 += __shfl_xor(s4, 2);
        s4 += __shfl_xor(s4, 4);
        s4 += __shfl_xor(s4, 8);
        if (l16 == 0) {
          int s = st * 16 + quad * 4 + r;
          // concat: L0 s64:128 -> 0:64 ; L1 s64:128 -> 64:128 ; L2 s -> 128:256
          if (L == 2)       out[(size_t)(bbase + b) * 256 + 128 + s] = s4;
          else if (s >= 64) out[(size_t)(bbase + b) * 256 + L * 64 + (s - 64)] = s4;
        }
      }
    }
    if (L < 2) __syncthreads();   // handoff writes visible before next-layer Bf loads
  }
}

extern "C" void kernel_launch(void* const* d_in, const int* in_sizes, int n_in,
                              void* d_out, int out_size, void* d_ws, size_t ws_size,
                              hipStream_t stream) {
  (void)in_sizes; (void)n_in; (void)out_size; (void)ws_size;
  const float* x  = (const float*)d_in[0];
  const float* w0 = (const float*)d_in[1];
  const float* b0 = (const float*)d_in[2];
  const float* w1 = (const float*)d_in[3];
  const float* b1 = (const float*)d_in[4];
  const float* w2 = (const float*)d_in[5];
  const float* b2 = (const float*)d_in[6];
  uint16_t* wt    = (uint16_t*)d_ws;   // 117 * 8192 * 2 = 1,916,928 B

  cin_prepass<<<NHB, 256, 0, stream>>>(w0, w1, w2, wt);
  cin_main<<<256, 512, 0, stream>>>(x, b0, b1, b2, wt, (float*)d_out);
}

// Round 8
// 144.325 us; speedup vs baseline: 10.3250x; 1.0223x over previous
//
#include <hip/hip_runtime.h>
#include <stdint.h>
#include <stddef.h>

// ---------------- problem constants ----------------
// B=2048, F0=39, D=16, layers 128/128/128, xk halves to 64 after each layer.
// Factored form: y_h[s,d] = sum_k W[h,k,s]*xk[b,k,d] (MFMA: A=W static, B=xk
// h-invariant -> register-cached per layer); z[b,s,d] = sum_h x0[b,h,d]*y_h[s,d]
// (4 fmac per (b,h), x0 in full f32). R8: 512 blocks x 4 batches (was 256 x 8)
// -> 2 blocks/CU, 4 waves/SIMD: R7's per-step vmcnt stall (~45% of cycles,
// only 2 waves/SIMD to hide ~300cyc L2 latency) now covered by TLP.
#define F0N  39
#define SN   128
#define NB   4             // batches per block
#define X0TS 44            // f32 stride of X0T row (b,d): 39+pad, 16B-aligned
#define XKTS 72            // u16 stride of XKT row (b,d): 64+8 pad, 16B-aligned
#define WBLK 8192          // u16 per (L,h) W block: 8 s-tiles x 2 chunks x 512
#define NHB  117           // 3*39 prepass blocks

typedef __attribute__((ext_vector_type(8))) short short8;   // MFMA A/B operand
typedef __attribute__((ext_vector_type(4))) float floatx4;  // MFMA accumulator

__device__ __forceinline__ uint16_t f2bf(float f) {         // RNE f32->bf16
  uint32_t u = __float_as_uint(f);
  u += 0x7fffu + ((u >> 16) & 1u);
  return (uint16_t)(u >> 16);
}

// ---------------- pre-pass: W fp32 -> bf16 A-fragment blocks (R6/R7-verified) ----------------
// One block per (L,h). Block layout (u16 idx in 8192):
//   (st*2+ch)*512 + lane*8 + j  where value = W[h][k=ch*32+quad*8+j][s=st*16+l16]
__global__ __launch_bounds__(256) void cin_prepass(
    const float* __restrict__ w0, const float* __restrict__ w1,
    const float* __restrict__ w2, uint16_t* __restrict__ wt) {
  __shared__ float T[64 * 132];               // [k][s], +4 pad floats per row
  const int bc = blockIdx.x;                  // 0..116
  const int L = bc / F0N;
  const int h = bc - L * F0N;
  const float* W = (L == 0) ? w0 : ((L == 1) ? w1 : w2);
  const int fk = (L == 0) ? 39 : 64;
  const int tid = threadIdx.x;

  for (int e = tid; e < 8192; e += 256) {     // coalesced fp32 read, k padded to 64
    int k = e >> 7, s = e & 127;
    T[k * 132 + s] = (k < fk) ? W[(h * fk + k) * SN + s] : 0.0f;
  }
  __syncthreads();
  uint32_t* dst = (uint32_t*)(wt + (size_t)bc * WBLK);
  for (int i = tid; i < 4096; i += 256) {     // coalesced u32 writes, frag order
    int frag = i >> 8, w = i & 255;
    int st = frag >> 1, ch = frag & 1;
    int ln = w >> 2, jp = w & 3;
    int quad = ln >> 4, l16 = ln & 15;
    int k0 = ch * 32 + quad * 8 + jp * 2;
    int s = st * 16 + l16;
    dst[i] = (uint32_t)f2bf(T[k0 * 132 + s]) | ((uint32_t)f2bf(T[(k0 + 1) * 132 + s]) << 16);
  }
}

// ---------------- fused main kernel ----------------
// 512 blocks x 512 threads (8 waves), 2 blocks/CU, 4 waves/SIMD. Block owns
// NB=4 batches; wave st owns s-tile [st*16, st*16+16) x all 4 b. Per layer:
// Bf (xk B-frags) register-cached; per h: 2 coalesced global W-frag loads
// (dist-1 register prefetch, no barriers in h-loop), float4 x0 reads per 4 h,
// 8 MFMA + 16 fmac. h runs to 40; h=39 has xs=0 (X0T pad) so its (arbitrary
// but finite) W contributes 0; its prefetch seeds the next layer's h0.
// D-layout: D[s=st*16+quad*4+r][d=l16]; sum_d = shfl_xor over l16 bits.
__global__ __launch_bounds__(512, 4) void cin_main(
    const float* __restrict__ x,       // (2048, 39, 16) fp32
    const float* __restrict__ bias0, const float* __restrict__ bias1,
    const float* __restrict__ bias2,
    const uint16_t* __restrict__ wt,   // A-frag bf16 weights (d_ws)
    float* __restrict__ out) {         // (2048, 256) fp32

  __shared__ __align__(16) float    X0T[NB * 16 * X0TS];  // x0[b][d][h] f32, 11264 B
  __shared__ __align__(16) uint16_t XKT[NB * 16 * XKTS];  // xk[b][d][k] bf16, 9216 B

  const int tid  = threadIdx.x;
  const int lane = tid & 63;
  const int st   = tid >> 6;           // wave index = s-tile
  const int l16  = lane & 15;          // = d (output col)
  const int quad = lane >> 4;
  const int bbase = blockIdx.x * NB;

  // zero X0T (h-pad 39..43 must be 0 -> xs=0 at h=39) and XKT (k-pad for L0)
  {
    float* p = X0T;                    // 2816 floats
#pragma unroll
    for (int i = 0; i < 6; i++) { int e = tid + 512 * i; if (e < 2816) p[e] = 0.f; }
    uint32_t* q = (uint32_t*)XKT;      // 2304 dwords
#pragma unroll
    for (int i = 0; i < 5; i++) { int e = tid + 512 * i; if (e < 2304) q[e] = 0u; }
  }
  __syncthreads();

  // fill X0T[b][d][h] = x[bbase+b][h][d]  (coalesced read, LDS transpose-scatter)
#pragma unroll
  for (int it = 0; it < 5; ++it) {
    int e = tid + it * 512;            // e = (b*39 + h)*16 + d, total 2496
    if (e < NB * F0N * 16) {
      float v = x[(size_t)bbase * (F0N * 16) + e];
      int d = e & 15, p = e >> 4;
      int b = p / F0N, h = p - b * F0N;
      X0T[(b * 16 + d) * X0TS + h] = v;
    }
  }
  __syncthreads();

  // build layer-0 XKT[b][d][k] = bf16(x0[b][k][d]) for k<39, 0 for k in [39,64)
  if (tid < 256) {
    int b = tid >> 6, d = (tid >> 2) & 15, kg = tid & 3;
    const float* src = &X0T[(b * 16 + d) * X0TS];
    uint32_t* drow = (uint32_t*)&XKT[(b * 16 + d) * XKTS + kg * 16];
#pragma unroll
    for (int i2 = 0; i2 < 8; i2++) {
      int k0 = kg * 16 + i2 * 2;
      uint32_t lo = (k0 < 39)     ? (uint32_t)f2bf(src[k0])     : 0u;
      uint32_t hi = (k0 + 1 < 39) ? (uint32_t)f2bf(src[k0 + 1]) : 0u;
      drow[i2] = lo | (hi << 16);
    }
  }
  __syncthreads();   // XKT build visible for Bf loads

  // per-wave global W base (u16 units)
  const uint16_t* wlane = wt + st * 1024 + (size_t)lane * 8;
  const float*    xr    = &X0T[l16 * X0TS];    // + b*16*X0TS + h

  // seed prefetch: (L0, h0)
  short8 Wc0 = *(const short8*)(wlane);
  short8 Wc1 = *(const short8*)(wlane + 512);

#pragma unroll 1
  for (int L = 0; L < 3; ++L) {
    // register-cache B-fragments (h-invariant within layer)
    short8 Bf0[NB], Bf1[NB];
#pragma unroll
    for (int b = 0; b < NB; ++b) {
      const uint16_t* r = XKT + (b * 16 + l16) * XKTS + quad * 8;
      Bf0[b] = *(const short8*)r;          // k 0..31 chunk
      Bf1[b] = *(const short8*)(r + 32);   // k 32..63 chunk
    }
    const float* bp = (L == 0) ? bias0 : ((L == 1) ? bias1 : bias2);
    float bvr[4];
#pragma unroll
    for (int r = 0; r < 4; ++r) bvr[r] = bp[st * 16 + quad * 4 + r];

    floatx4 z[NB] = {};
    const floatx4 zero4 = {0.f, 0.f, 0.f, 0.f};

#pragma unroll 1
    for (int h4 = 0; h4 < 10; ++h4) {
      float4 xv[NB];                   // x0 for h = h4*4 .. h4*4+3 (h>=39 -> 0 pad)
#pragma unroll
      for (int b = 0; b < NB; ++b)
        xv[b] = *(const float4*)&X0T[(b * 16 + l16) * X0TS + h4 * 4];

#pragma unroll
      for (int hi = 0; hi < 4; ++hi) {
        const int h = h4 * 4 + hi;
        // distance-1 prefetch of next h (or next layer's h0); wave-uniform addr
        short8 Wn0, Wn1;
        {
          int Ln = L, hh = h + 1;
          if (hh >= 39) { if (L < 2) { Ln = L + 1; hh = 0; } else hh = 38; }
          const uint16_t* wl = wlane + (size_t)(Ln * F0N + hh) * WBLK;
          Wn0 = *(const short8*)wl;
          Wn1 = *(const short8*)(wl + 512);
        }

#pragma unroll
        for (int b = 0; b < NB; ++b) {
          floatx4 y = __builtin_amdgcn_mfma_f32_16x16x32_bf16(Wc0, Bf0[b], zero4, 0, 0, 0);
          y = __builtin_amdgcn_mfma_f32_16x16x32_bf16(Wc1, Bf1[b], y, 0, 0, 0);
          const float xs = (hi == 0) ? xv[b].x : (hi == 1) ? xv[b].y
                         : (hi == 2) ? xv[b].z : xv[b].w;
#pragma unroll
          for (int r = 0; r < 4; ++r) z[b][r] += xs * y[r];
        }
        Wc0 = Wn0;
        Wc1 = Wn1;
      }
    }

    // ---- epilogue: bias+relu; xk handoff; sum_d (over l16) -> out ----
#pragma unroll
    for (int b = 0; b < NB; ++b) {
#pragma unroll
      for (int r = 0; r < 4; ++r) {
        float t = fmaxf(z[b][r] + bvr[r], 0.f);
        if (L < 2 && st < 4)               // xk = relu(z)[:, :64]; k = s < 64
          XKT[(b * 16 + l16) * XKTS + st * 16 + quad * 4 + r] = f2bf(t);
        float s4 = t;                       // reduce over d = l16 (bits 0..3)
        s4 += __shfl_xor(s4, 1);
        s4 += __shfl_xor(s4, 2);
        s4 += __shfl_xor(s4, 4);
        s4 += __shfl_xor(s4, 8);
        if (l16 == 0) {
          int s = st * 16 + quad * 4 + r;
          // concat: L0 s64:128 -> 0:64 ; L1 s64:128 -> 64:128 ; L2 s -> 128:256
          if (L == 2)       out[(size_t)(bbase + b) * 256 + 128 + s] = s4;
          else if (s >= 64) out[(size_t)(bbase + b) * 256 + L * 64 + (s - 64)] = s4;
        }
      }
    }
    if (L < 2) __syncthreads();   // handoff writes visible before next-layer Bf loads
  }
}

extern "C" void kernel_launch(void* const* d_in, const int* in_sizes, int n_in,
                              void* d_out, int out_size, void* d_ws, size_t ws_size,
                              hipStream_t stream) {
  (void)in_sizes; (void)n_in; (void)out_size; (void)ws_size;
  const float* x  = (const float*)d_in[0];
  const float* w0 = (const float*)d_in[1];
  const float* b0 = (const float*)d_in[2];
  const float* w1 = (const float*)d_in[3];
  const float* b1 = (const float*)d_in[4];
  const float* w2 = (const float*)d_in[5];
  const float* b2 = (const float*)d_in[6];
  uint16_t* wt    = (uint16_t*)d_ws;   // 117 * 8192 * 2 = 1,916,928 B

  cin_prepass<<<NHB, 256, 0, stream>>>(w0, w1, w2, wt);
  cin_main<<<512, 512, 0, stream>>>(x, b0, b1, b2, wt, (float*)d_out);
}